// Round 5
// baseline (2052.523 us; speedup 1.0000x reference)
//
#include <hip/hip_runtime.h>
#include <math.h>

// ConvGRU fused per-timestep kernel, v4: all-LDS inner loop (no SMEM drains).
// x: (4,16,64,64,64) f32, Wx: (96,16,3,3), bx: (96), Wh: (96,32,3,3).
// r-gate is dead in the reference: only gate rows [0,32) (z) and [64,96) (n).
// Block = 16x64 pixel tile, ONE output channel c; 4 vertical px/thread.
// Inputs staged in LDS in 6 chunks of 8 channels; this channel's weights
// (z+n: 864 floats) staged to LDS ONCE at block start, so the unrolled inner
// loop reads pixels AND weights from LDS only -> in-order lgkmcnt, fine-grained
// waits instead of the s_load-induced lgkmcnt(0) drains of v2/v3.
// h ping-pongs d_out <-> d_ws; t=63 writes d_out.

#define LW 72
#define DOFF 4
#define ROWS 18                      // 16 tile rows + 2 halo
#define PIX_FLOATS (8 * ROWS * LW)   // 10368 floats = 41.5 KB
#define WPAD 12                      // filter padded 9 -> 12 floats (16B align)
#define W_FLOATS (6 * 8 * 2 * WPAD)  // 1152 floats = 4.6 KB

__global__ __launch_bounds__(256, 2) void convgru_step(
    const float* __restrict__ x, const float* __restrict__ Wx,
    const float* __restrict__ bx, const float* __restrict__ Wh,
    const float* __restrict__ hsrc, float* __restrict__ hdst, int t)
{
    __shared__ float plds[PIX_FLOATS];
    __shared__ float wlds[W_FLOATS];
    const int tx   = threadIdx.x;
    const int y0   = blockIdx.x * 16;      // tile rows y0..y0+15
    const int c    = blockIdx.y;           // output channel (uniform)
    const int b    = blockIdx.z;
    const int quad = tx >> 6;              // 0..3: rows quad*4..quad*4+3
    const int col  = tx & 63;

    // prefetch h_prev for the 4 output pixels (coalesced, latency hidden)
    float hprev[4];
    #pragma unroll
    for (int j = 0; j < 4; ++j)
        hprev[j] = hsrc[(size_t)(b * 32 + c) * 4096 + (y0 + quad * 4 + j) * 64 + col];

    // ---- one-time: stage this block's weights into LDS ----
    // layout: wlds[((chunk*8 + cin8)*2 + gate)*12 + tap], tap 9..11 = 0 pad
    for (int i = tx; i < W_FLOATS; i += 256) {
        int tap  = i % WPAD;
        int rest = i / WPAD;
        int gate = rest & 1;  rest >>= 1;
        int cin8 = rest & 7;
        int chunk = rest >> 3;
        float val = 0.0f;
        if (tap < 9) {
            int grow = (gate ? 64 + c : c);
            if (chunk < 2)
                val = Wx[((size_t)grow * 16 + chunk * 8 + cin8) * 9 + tap];
            else
                val = Wh[((size_t)grow * 32 + (chunk - 2) * 8 + cin8) * 9 + tap];
        }
        wlds[i] = val;
    }

    // zero halo columns once (144 rows x 2 cols; staging never writes them)
    #pragma unroll
    for (int i = 0; i < 2; ++i) {
        int task = i * 256 + tx;
        if (task < 288)
            plds[(task >> 1) * LW + ((task & 1) ? (DOFF + 64) : (DOFF - 1))] = 0.0f;
    }

    float acc[8];                          // [px j][gate z=0,n=1]
    const float bz = bx[c], bn = bx[64 + c];
    #pragma unroll
    for (int j = 0; j < 4; ++j) { acc[2 * j] = bz; acc[2 * j + 1] = bn; }

    for (int chunk = 0; chunk < 6; ++chunk) {
        const float* src;
        size_t chanStride;
        if (chunk < 2) {
            src = x + ((size_t)(b * 16 + chunk * 8) * 64 + t) * 4096;
            chanStride = (size_t)64 * 4096;
        } else {
            src = hsrc + (size_t)(b * 32 + (chunk - 2) * 8) * 4096;
            chanStride = 4096;
        }

        __syncthreads();  // prev compute (or weight/halo staging) done before restage
        // stage 8 channels x 18 halo rows x 64 cols as float4 (2304 tasks)
        #pragma unroll
        for (int i = 0; i < 9; ++i) {
            int task = i * 256 + tx;
            int f4   = task & 15;
            int rowg = task >> 4;          // 0..143 = ch*18 + r
            int ch   = rowg / 18;
            int r    = rowg - ch * 18;
            int yy   = y0 - 1 + r;
            float4 v = make_float4(0.f, 0.f, 0.f, 0.f);
            if ((unsigned)yy < 64u)
                v = *(const float4*)(src + ch * chanStride + yy * 64 + f4 * 4);
            *(float4*)&plds[rowg * LW + DOFF + f4 * 4] = v;   // 16B-aligned
        }
        __syncthreads();

        #pragma unroll
        for (int cin = 0; cin < 8; ++cin) {
            const float* lb = &plds[(cin * ROWS + quad * 4) * LW + DOFF + col - 1];
            float v[6][3];
            #pragma unroll
            for (int rr = 0; rr < 6; ++rr) {
                v[rr][0] = lb[rr * LW];
                v[rr][1] = lb[rr * LW + 1];
                v[rr][2] = lb[rr * LW + 2];
            }
            const float* wz = &wlds[((chunk * 8 + cin) * 2 + 0) * WPAD];
            const float* wn = &wlds[((chunk * 8 + cin) * 2 + 1) * WPAD];
            float wzr[9], wnr[9];
            #pragma unroll
            for (int k = 0; k < 9; ++k) { wzr[k] = wz[k]; wnr[k] = wn[k]; }
            #pragma unroll
            for (int j = 0; j < 4; ++j) {
                #pragma unroll
                for (int kr = 0; kr < 3; ++kr) {
                    #pragma unroll
                    for (int kc = 0; kc < 3; ++kc) {
                        acc[2 * j]     = fmaf(v[j + kr][kc], wzr[kr * 3 + kc], acc[2 * j]);
                        acc[2 * j + 1] = fmaf(v[j + kr][kc], wnr[kr * 3 + kc], acc[2 * j + 1]);
                    }
                }
            }
        }
    }

    #pragma unroll
    for (int j = 0; j < 4; ++j) {
        const int p = (y0 + quad * 4 + j) * 64 + col;
        float z = 1.0f / (1.0f + __expf(-acc[2 * j]));
        float e = __expf(2.0f * acc[2 * j + 1]);
        float n = 1.0f - 2.0f / (e + 1.0f);          // tanh, overflow-safe
        hdst[(size_t)(b * 32 + c) * 4096 + p] = (1.0f - z) * hprev[j] + z * n;
    }
}

extern "C" void kernel_launch(void* const* d_in, const int* in_sizes, int n_in,
                              void* d_out, int out_size, void* d_ws, size_t ws_size,
                              hipStream_t stream) {
    const float* x  = (const float*)d_in[0];
    const float* Wx = (const float*)d_in[1];
    const float* bx = (const float*)d_in[2];
    const float* Wh = (const float*)d_in[3];
    float* out = (float*)d_out;
    float* ws  = (float*)d_ws;

    // h0 = zeros in d_out (even t: read out -> write ws; odd t: read ws -> write out;
    // t=63 odd => final h lands in d_out).
    hipMemsetAsync(d_out, 0, (size_t)524288 * sizeof(float), stream);

    dim3 grid(4, 32, 4), block(256);
    for (int t = 0; t < 64; ++t) {
        const float* src = (t & 1) ? ws : out;
        float*       dst = (t & 1) ? out : ws;
        hipLaunchKernelGGL(convgru_step, grid, block, 0, stream,
                           x, Wx, bx, Wh, src, dst, t);
    }
}